// Round 7
// baseline (244.878 us; speedup 1.0000x reference)
//
#include <hip/hip_runtime.h>

#define B_ 32
#define F_ 256
#define T_ 2048
#define K_ 1024
#define M_ (B_*T_)     // 65536 points

#define MARGIN 0.45f   // covers 2*(fp16-screen tail ~0.1) + quant 0.0625 + slack
#define CAP 128

typedef _Float16 f16x8 __attribute__((ext_vector_type(8)));
typedef float f32x4 __attribute__((ext_vector_type(4)));

// ---- prep: emb [K,F] f32 -> cprep fp16 [K,F]; c2 (fp64 exact + fp32) ----
__global__ void k_prep(const float* __restrict__ emb, unsigned short* __restrict__ cprep,
                       double* __restrict__ c2d, float* __restrict__ c2f) {
    int k = blockIdx.x;      // 1024 blocks, 64 threads
    int l = threadIdx.x;
    float4 v = *reinterpret_cast<const float4*>(emb + k * F_ + l * 4);
    union { _Float16 h[4]; unsigned long long ll; } cv;
    cv.h[0] = (_Float16)v.x; cv.h[1] = (_Float16)v.y;
    cv.h[2] = (_Float16)v.z; cv.h[3] = (_Float16)v.w;
    *reinterpret_cast<unsigned long long*>(cprep + k * F_ + l * 4) = cv.ll;
    double s = (double)v.x * v.x + (double)v.y * v.y
             + (double)v.z * v.z + (double)v.w * v.w;
    #pragma unroll
    for (int d = 1; d < 64; d <<= 1) s += __shfl_xor(s, d);
    if (l == 0) { c2d[k] = s; c2f[k] = (float)s; }
}

// B-fragment load straight from global (L1/L2-resident cprep); 8 slices, 16B/lane.
#define LOADB(dst, c2n, tt) {                                                    \
    const unsigned short* bp = cprep + ((tt) * 16 + row) * F_ + qd * 8;          \
    _Pragma("unroll")                                                            \
    for (int s_ = 0; s_ < 8; ++s_)                                               \
        dst[s_] = *reinterpret_cast<const f16x8*>(bp + s_ * 32);                 \
    c2n = c2f[(tt) * 16 + row];                                                  \
}

// 16 MFMA on one 16-code tile + packed-int top-3 epilogue (validated round-4 math)
#define COMPUTE(bf, c2v, tt) {                                                   \
    const int kk = (tt) * 16 + row;                                              \
    f32x4 acc0 = {0.f, 0.f, 0.f, 0.f};                                           \
    f32x4 acc1 = {0.f, 0.f, 0.f, 0.f};                                           \
    _Pragma("unroll")                                                            \
    for (int s_ = 0; s_ < 8; ++s_) {                                             \
        acc0 = __builtin_amdgcn_mfma_f32_16x16x32_f16(ah0[s_], bf[s_], acc0, 0, 0, 0); \
        acc1 = __builtin_amdgcn_mfma_f32_16x16x32_f16(ah1[s_], bf[s_], acc1, 0, 0, 0); \
    }                                                                            \
    _Pragma("unroll")                                                            \
    for (int r_ = 0; r_ < 4; ++r_) {                                             \
        {                                                                        \
            float q = fmaf(acc0[r_], -2.0f, c2v + a2s[r_]);                      \
            int vi = (__float_as_int(q) & 0xFFFFFC00) | kk;                      \
            int t1 = max(m1i[r_], vi); m1i[r_] = min(m1i[r_], vi);               \
            int t2 = max(m2i[r_], t1); m2i[r_] = min(m2i[r_], t1);               \
            m3i[r_] = min(m3i[r_], t2);                                          \
        }                                                                        \
        {                                                                        \
            float q = fmaf(acc1[r_], -2.0f, c2v + a2s[4 + r_]);                  \
            int vi = (__float_as_int(q) & 0xFFFFFC00) | kk;                      \
            int t1 = max(m1i[4 + r_], vi); m1i[4 + r_] = min(m1i[4 + r_], vi);   \
            int t2 = max(m2i[4 + r_], t1); m2i[4 + r_] = min(m2i[4 + r_], t1);   \
            m3i[4 + r_] = min(m3i[4 + r_], t2);                                  \
        }                                                                        \
    }                                                                            \
}

// ---- main: fp16 MFMA screen, barrier-free 1-wave blocks, fp64 rescore ----
__global__ __launch_bounds__(64, 2) void k_argmin(
    const float* __restrict__ x, const float* __restrict__ emb,
    const unsigned short* __restrict__ cprep,
    const double* __restrict__ c2d, const float* __restrict__ c2f,
    int* __restrict__ idx_out, double* __restrict__ partials)
{
    __shared__ int cand_cnt;
    __shared__ int cand_pk[CAP];
    __shared__ double cand_q[CAP];
    __shared__ int res_k[32];

    const int l = threadIdx.x;            // 0..63 (one wave)
    const int bid = blockIdx.x;           // 2048 blocks, 32 points each
    const int b = bid >> 6;
    const int t0 = (bid & 63) * 32;
    const int row = l & 15;               // A row (point) / B col (code) within tile
    const int qd = l >> 4;                // k-quarter

    if (l == 0) cand_cnt = 0;

    // ---- load A (x) into fp16 fragments; per-lane partial sum(x^2) ----
    const float* xb = x + (size_t)b * (F_ * T_) + t0 + row + (size_t)qd * 8 * T_;
    float xsql = 0.f, xsqh = 0.f;
    f16x8 ah0[8], ah1[8];
    #pragma unroll
    for (int s = 0; s < 8; ++s) {
        #pragma unroll
        for (int j = 0; j < 8; ++j) {
            size_t fo = (size_t)(s * 32 + j) * T_;
            float v0 = xb[fo];
            float v1 = xb[fo + 16];
            ah0[s][j] = (_Float16)v0;
            ah1[s][j] = (_Float16)v1;
            xsql = fmaf(v0, v0, xsql);
            xsqh = fmaf(v1, v1, xsqh);
        }
    }
    // full a2 per point: sum partials across the 4 qd groups (same row)
    float xl = xsql, xh = xsqh;
    xl += __shfl_xor(xl, 16); xl += __shfl_xor(xl, 32);
    xh += __shfl_xor(xh, 16); xh += __shfl_xor(xh, 32);
    // redistribute to C/D slot layout: slot r -> point qd*4 + r (lane qd*4+r holds it)
    float a2s[8];
    #pragma unroll
    for (int r = 0; r < 4; ++r) {
        a2s[r]     = __shfl(xl, qd * 4 + r);
        a2s[4 + r] = __shfl(xh, qd * 4 + r);
    }

    int m1i[8], m2i[8], m3i[8];
    #pragma unroll
    for (int i = 0; i < 8; ++i) { m1i[i] = 0x7FFFFFFF; m2i[i] = 0x7FFFFFFF; m3i[i] = 0x7FFFFFFF; }

    // ---- main loop: unroll-2, two named register sets (no dynamic indexing) ----
    f16x8 bA[8], bB[8];
    float c2A, c2B;
    LOADB(bA, c2A, 0);
    #pragma unroll 1
    for (int t = 0; t < 64; t += 2) {
        LOADB(bB, c2B, t + 1);
        COMPUTE(bA, c2A, t);
        if (t + 2 < 64) LOADB(bA, c2A, t + 2);
        COMPUTE(bB, c2B, t + 1);
    }

    // ---- per-point group-reduce, provisional winner, candidate push ----
    double loss_acc = 0.0;
    #pragma unroll
    for (int i = 0; i < 8; ++i) {
        int gm = m1i[i];
        #pragma unroll
        for (int d = 1; d < 16; d <<= 1) { int o = __shfl_xor(gm, d); gm = min(gm, o); }
        float thr = __int_as_float(gm & 0xFFFFFC00) + MARGIN;
        bool in1 = __int_as_float(m1i[i] & 0xFFFFFC00) <= thr;
        bool in2 = __int_as_float(m2i[i] & 0xFFFFFC00) <= thr;   // NaN-safe: INT_MAX -> NaN -> false
        bool in3 = __int_as_float(m3i[i] & 0xFFFFFC00) <= thr;
        unsigned long long b1 = __ballot(in1), b2 = __ballot(in2), b3 = __ballot(in3);
        int sh = l & 48;
        int cnt = __popcll((b1 >> sh) & 0xFFFFull) + __popcll((b2 >> sh) & 0xFFFFull)
                + __popcll((b3 >> sh) & 0xFFFFull);
        int p = (i >> 2) * 16 + qd * 4 + (i & 3);
        if ((l & 15) == 0) {
            res_k[p] = gm & 1023;
            loss_acc += (double)__int_as_float((gm & 0xFFFFFC00) | 512);  // midpoint restore
        }
        if (cnt >= 2) {   // near-tie: push every in-margin candidate for exact rescore
            if (in1) { int s_ = atomicAdd(&cand_cnt, 1); if (s_ < CAP) cand_pk[s_] = (p << 10) | (m1i[i] & 1023); }
            if (in2) { int s_ = atomicAdd(&cand_cnt, 1); if (s_ < CAP) cand_pk[s_] = (p << 10) | (m2i[i] & 1023); }
            if (in3) { int s_ = atomicAdd(&cand_cnt, 1); if (s_ < CAP) cand_pk[s_] = (p << 10) | (m3i[i] & 1023); }
        }
    }
    __syncthreads();   // single wave: compiles to waitcnt only

    // ---- fp64 exact rescore (whole wave per candidate; candidates are rare) ----
    int total = cand_cnt; if (total > CAP) total = CAP;
    for (int ci = 0; ci < total; ++ci) {
        int pk = cand_pk[ci];
        int p = pk >> 10, k = pk & 1023;
        const float* xp = x + (size_t)b * (F_ * T_) + t0 + p;
        const float4 ev = *reinterpret_cast<const float4*>(emb + k * F_ + l * 4);
        double s = 0.0;
        s += (double)xp[(size_t)(l * 4 + 0) * T_] * (double)ev.x;
        s += (double)xp[(size_t)(l * 4 + 1) * T_] * (double)ev.y;
        s += (double)xp[(size_t)(l * 4 + 2) * T_] * (double)ev.z;
        s += (double)xp[(size_t)(l * 4 + 3) * T_] * (double)ev.w;
        #pragma unroll
        for (int d = 1; d < 64; d <<= 1) s += __shfl_xor(s, d);
        if (l == 0) cand_q[ci] = c2d[k] - 2.0 * s;   // per-point a2 const: argmin-equivalent
    }
    __syncthreads();

    // ---- owner scan: exact winner for rescored points; write idx ----
    if (l < 32) {
        double bq = 1e300; int bk = -1; bool any = false;
        for (int ci = 0; ci < total; ++ci) {
            int pk = cand_pk[ci];
            if ((pk >> 10) == l) {
                double q = cand_q[ci]; int k = pk & 1023;
                if (q < bq || (q == bq && k < bk)) { bq = q; bk = k; }
                any = true;
            }
        }
        idx_out[b * T_ + t0 + l] = any ? bk : res_k[l];
    }

    // ---- wave loss partial (dist already includes a2; only lanes l&15==0 nonzero) ----
    #pragma unroll
    for (int d = 1; d < 64; d <<= 1) loss_acc += __shfl_xor(loss_acc, d);
    if (l == 0) partials[bid] = loss_acc;
}

__global__ void k_loss(const double* __restrict__ partials, float* __restrict__ out_losses) {
    __shared__ double redd[256];
    int tid = threadIdx.x;
    double s = 0.0;
    #pragma unroll
    for (int i = 0; i < 8; ++i) s += partials[tid + i * 256];
    redd[tid] = s;
    __syncthreads();
    for (int st = 128; st > 0; st >>= 1) {
        if (tid < st) redd[tid] += redd[tid + st];
        __syncthreads();
    }
    if (tid == 0) {
        float loss = (float)(redd[0] / ((double)F_ * (double)M_));
        out_losses[0] = loss;
        out_losses[1] = loss;
    }
}

// ---- gather via LDS transpose: coalesced emb row reads, contiguous out writes ----
__global__ __launch_bounds__(256) void k_gather(
    const float* __restrict__ emb, const int* __restrict__ idx,
    float* __restrict__ out)
{
    __shared__ float tile[32][257];   // +1 pad: conflict-free transposed reads
    __shared__ int karr[32];

    const int tid = threadIdx.x;
    const int bid = blockIdx.x;       // 2048 blocks: (b, 32-t window)
    const int b = bid >> 6;
    const int t0 = (bid & 63) * 32;

    if (tid < 32) karr[tid] = idx[b * T_ + t0 + tid];
    __syncthreads();

    #pragma unroll
    for (int pass = 0; pass < 8; ++pass) {
        int r = pass * 4 + (tid >> 6);          // 4 rows per pass (one per wave)
        int c = (tid & 63) * 4;
        *reinterpret_cast<float4*>(&tile[r][c]) =
            *reinterpret_cast<const float4*>(emb + karr[r] * F_ + c);
    }
    __syncthreads();

    #pragma unroll
    for (int pass = 0; pass < 8; ++pass) {
        int f = pass * 32 + (tid >> 3);
        int t4 = (tid & 7) * 4;
        float4 v;
        v.x = tile[t4 + 0][f];
        v.y = tile[t4 + 1][f];
        v.z = tile[t4 + 2][f];
        v.w = tile[t4 + 3][f];
        *reinterpret_cast<float4*>(out + ((size_t)b * F_ + f) * T_ + t0 + t4) = v;
    }
}

extern "C" void kernel_launch(void* const* d_in, const int* in_sizes, int n_in,
                              void* d_out, int out_size, void* d_ws, size_t ws_size,
                              hipStream_t stream) {
    const float* x   = (const float*)d_in[0];
    const float* emb = (const float*)d_in[1];
    float* out = (float*)d_out;

    double* c2d = (double*)d_ws;                                // 8 KB
    double* partials = c2d + K_;                                // 16 KB (2048)
    unsigned short* cprep = (unsigned short*)(partials + 2048); // 512 KB
    float* c2f = (float*)(cprep + K_ * F_);                     // 4 KB
    int* idx = (int*)(c2f + K_);                                // 256 KB

    k_prep<<<K_, 64, 0, stream>>>(emb, cprep, c2d, c2f);
    k_argmin<<<M_ / 32, 64, 0, stream>>>(x, emb, cprep, c2d, c2f, idx, partials);
    k_loss<<<1, 256, 0, stream>>>(partials, out + (size_t)M_ * F_);
    k_gather<<<M_ / 32, 256, 0, stream>>>(emb, idx, out);
}